// Round 7
// baseline (17.397 us; speedup 1.0000x reference)
//
#include <hip/hip_runtime.h>
#include <math.h>

// ---------------------------------------------------------------------------
// QuantumResidualRegressor R7: 2 samples per thread, packed f32x2 math.
//   X-basis collapsed circuit (validated R4-R6). Each thread computes samples
//   t and t+B/2 with both packed into the two lanes of f32x2 ops -> most VALU
//   serves 2 samples; per-wave s_load stalls amortized over 2 samples; 2-deep
//   ILP everywhere. 1024 waves (1/SIMD), VGPR budget relaxed to 512.
// ---------------------------------------------------------------------------

typedef float f32x2 __attribute__((ext_vector_type(2)));

// X-basis CNOT-ring permutation (one layer) on 6-bit indices.
__host__ __device__ constexpr int Lmap(int j) {
    int b5=(j>>5)&1, b4=(j>>4)&1, b3=(j>>3)&1, b2=(j>>2)&1, b1=(j>>1)&1, b0=j&1;
    int o5=b5^b4, o4=b4^b3, o3=b3^b2, o2=b2^b1, o1=b1^b0, o0=b0^b5^b4;
    return (o5<<5)|(o4<<4)|(o3<<3)|(o2<<2)|(o1<<1)|o0;
}
__host__ __device__ constexpr int Linv(int j) {
    int o5=(j>>5)&1, o4=(j>>4)&1, o3=(j>>3)&1, o2=(j>>2)&1, o1=(j>>1)&1, o0=j&1;
    int b4 = o5^o4^o3^o2^o1^o0;
    int b5 = b4^o5;
    int b3 = b4^o4;
    int b2 = b3^o3;
    int b1 = b2^o2;
    int b0 = b1^o1;
    return (b5<<5)|(b4<<4)|(b3<<3)|(b2<<2)|(b1<<1)|b0;
}
__host__ __device__ constexpr int MPc(int q) {   // m'_q = L^{-3} (bit 5-q)
    int m = 1 << (5 - q);
    m = Linv(m); m = Linv(m); m = Linv(m);
    return m;
}
__host__ __device__ constexpr int popc6(int m) {
    int c = 0;
    for (int p = 0; p < 6; ++p) c += (m >> p) & 1;
    return c;
}

__device__ __forceinline__ float fast_rcp(float x) { return __builtin_amdgcn_rcpf(x); }

__device__ __forceinline__ f32x2 bc2(float s) { return (f32x2){s, s}; }

// tanh(x) = 1 - 2/(1+e^{2x}) per lane-pair (exp/rcp are per-half scalar units)
__device__ __forceinline__ f32x2 fast_tanh2(f32x2 x) {
    float eA = __expf(2.0f * x.x);
    float eB = __expf(2.0f * x.y);
    return (f32x2){ fmaf(-2.0f, fast_rcp(1.0f + eA), 1.0f),
                    fmaf(-2.0f, fast_rcp(1.0f + eB), 1.0f) };
}
// tanh-form GELU, packed where possible
__device__ __forceinline__ f32x2 fast_gelu2(f32x2 x) {
    f32x2 x2 = x * x;
    // (x + 0.044715 x^3) * 0.7978845608 = x * (0.79788456 + 0.035677408*x^2)
    f32x2 inner = x * __builtin_elementwise_fma(x2, bc2(0.0356774081f), bc2(0.7978845608f));
    f32x2 t = fast_tanh2(inner);
    return bc2(0.5f) * x * (bc2(1.0f) + t);
}

// z_q (packed 2 samples) = c_q * sum_r K[q*8+r] * prod_{free bits p} u2[p][bit]
template<int Q>
__device__ __forceinline__ f32x2 zq_eval2(const f32x2 (&u2)[6][2], const f32x2 (&u01)[6],
                                          const float (&K)[48]) {
    constexpr int mp = MPc(Q);
    constexpr int F  = (~mp) & 63;
    constexpr int nf = 6 - popc6(mp);
    f32x2 cq = bc2(1.0f);
    #pragma unroll
    for (int p = 0; p < 6; ++p) if ((mp >> p) & 1) cq *= u01[p];
    f32x2 acc = bc2(0.0f);
    #pragma unroll
    for (int r = 0; r < (1 << nf); ++r) {
        f32x2 t = bc2(K[Q * 8 + r]);
        int k = nf;
        #pragma unroll
        for (int p = 5; p >= 0; --p) if ((F >> p) & 1) { --k; t *= u2[p][(r >> k) & 1]; }
        acc += t;
    }
    return acc * cq;
}

__global__ __launch_bounds__(256) __attribute__((amdgpu_waves_per_eu(1, 2)))
void qrr_kernel(const float* __restrict__ features,
                const float* __restrict__ baseline,
                const float* __restrict__ enc_w1,
                const float* __restrict__ enc_b1,
                const float* __restrict__ enc_w2,
                const float* __restrict__ enc_b2,
                const float* __restrict__ q_weights,
                const float* __restrict__ head_w1,
                const float* __restrict__ head_b1,
                const float* __restrict__ head_w2,
                const float* __restrict__ head_b2,
                float* __restrict__ out,
                int half_n)
{
    __shared__ float phi[64];
    __shared__ __align__(16) float KTs[48];
    const int tid = threadIdx.x;

    // ---- stage A: uniform phases Phi_j (threads 0..63) ----
    if (tid < 64) {
        int jl = tid;
        float acc = 0.0f;
        for (int l = 0; l < 3; ++l) {
            for (int q = 0; q < 6; ++q)
                acc += q_weights[l * 6 + q] * (((jl >> (5 - q)) & 1) ? 0.5f : -0.5f);
            jl = Lmap(jl);
        }
        phi[tid] = acc;
    }
    __syncthreads();

    // ---- stage B: K~[q][r] (threads 0..47) ----
    if (tid < 48) {
        const int q = tid >> 3, r = tid & 7;
        const int mp = Linv(Linv(Linv(1 << (5 - q))));
        const int F  = (~mp) & 63;
        const int nf = __popc(F), pm = 6 - nf;
        float kv = 0.0f;
        if (r < (1 << nf)) {
            int jb = 0, k = nf;
            for (int p = 5; p >= 0; --p)
                if ((F >> p) & 1) { --k; if ((r >> k) & 1) jb |= 1 << p; }
            float s = 0.0f;
            for (int e = 0; e < (1 << pm); ++e) {
                int je = 0, kk = pm;
                for (int p = 5; p >= 0; --p)
                    if ((mp >> p) & 1) { --kk; if ((e >> kk) & 1) je |= 1 << p; }
                const int j0 = jb | je;
                s += __cosf(phi[j0 ^ mp] - phi[j0]);
            }
            kv = s * (1.0f / 64.0f);
        }
        KTs[tid] = kv;
    }
    __syncthreads();

    // thread t handles samples t and t+half_n (both streams coalesced)
    const int t = blockIdx.x * 256 + tid;
    if (t >= half_n) return;
    const int bA = t, bB = t + half_n;

    // ---- features: 8x dwordx4 per sample, pair into f32x2 (A,B) ----
    f32x2 f2[32];
    {
        const float4* fa = reinterpret_cast<const float4*>(features + (size_t)bA * 32);
        const float4* fb = reinterpret_cast<const float4*>(features + (size_t)bB * 32);
        #pragma unroll
        for (int k = 0; k < 8; ++k) {
            float4 va = fa[k];
            float4 vb = fb[k];
            f2[4*k+0] = (f32x2){va.x, vb.x};
            f2[4*k+1] = (f32x2){va.y, vb.y};
            f2[4*k+2] = (f32x2){va.z, vb.z};
            f2[4*k+3] = (f32x2){va.w, vb.w};
        }
    }
    const float baseA = baseline[bA];
    const float baseB = baseline[bB];

    // ---- encoder L1: [32]->[16] GELU; acc packed across samples ----
    f32x2 h2[16];
    #pragma unroll
    for (int o = 0; o < 16; ++o) h2[o] = bc2(enc_b1[o]);
    #pragma unroll
    for (int i = 0; i < 32; ++i) {
        #pragma unroll
        for (int o = 0; o < 16; ++o)
            h2[o] = __builtin_elementwise_fma(f2[i], bc2(enc_w1[i * 16 + o]), h2[o]);
    }
    #pragma unroll
    for (int o = 0; o < 16; ++o) h2[o] = fast_gelu2(h2[o]);

    // ---- encoder L2: [16]->[6] tanh(a)=w -> u2 = 1±sin(w), u01 = cos(w) ----
    f32x2 u2[6][2], u01[6];
    #pragma unroll
    for (int q = 0; q < 6; ++q) {
        f32x2 a = bc2(enc_b2[q]);
        #pragma unroll
        for (int i = 0; i < 16; ++i)
            a = __builtin_elementwise_fma(h2[i], bc2(enc_w2[i * 6 + q]), a);
        f32x2 w = fast_tanh2(a);
        f32x2 sn = { __sinf(w.x), __sinf(w.y) };
        f32x2 cs = { __cosf(w.x), __cosf(w.y) };
        const int p = 5 - q;                  // bit position of qubit q
        u2[p][0] = bc2(1.0f) + sn;
        u2[p][1] = bc2(1.0f) - sn;
        u01[p]   = cs;
    }

    // ---- pull K~ into registers now (after MLP, lower VGPR peak) ----
    float K[48];
    {
        const float4* kp = reinterpret_cast<const float4*>(KTs);
        #pragma unroll
        for (int i = 0; i < 12; ++i) {
            float4 v = kp[i];
            K[4*i+0] = v.x; K[4*i+1] = v.y; K[4*i+2] = v.z; K[4*i+3] = v.w;
        }
    }

    // ---- expvals via factored quadratic forms (packed) ----
    f32x2 z[6];
    z[0] = zq_eval2<0>(u2, u01, K);
    z[1] = zq_eval2<1>(u2, u01, K);
    z[2] = zq_eval2<2>(u2, u01, K);
    z[3] = zq_eval2<3>(u2, u01, K);
    z[4] = zq_eval2<4>(u2, u01, K);
    z[5] = zq_eval2<5>(u2, u01, K);

    // ---- head: [6]->[16] GELU ->[1] ----
    f32x2 hh2[16];
    #pragma unroll
    for (int o = 0; o < 16; ++o) hh2[o] = bc2(head_b1[o]);
    #pragma unroll
    for (int i = 0; i < 6; ++i) {
        #pragma unroll
        for (int o = 0; o < 16; ++o)
            hh2[o] = __builtin_elementwise_fma(z[i], bc2(head_w1[i * 16 + o]), hh2[o]);
    }
    f32x2 r2 = bc2(head_b2[0]);
    #pragma unroll
    for (int o = 0; o < 16; ++o)
        r2 = __builtin_elementwise_fma(fast_gelu2(hh2[o]), bc2(head_w2[o]), r2);

    out[bA] = baseA + r2.x;
    out[bB] = baseB + r2.y;
}

extern "C" void kernel_launch(void* const* d_in, const int* in_sizes, int n_in,
                              void* d_out, int out_size, void* d_ws, size_t ws_size,
                              hipStream_t stream) {
    const float* features = (const float*)d_in[0];
    const float* baseline = (const float*)d_in[1];
    const float* enc_w1   = (const float*)d_in[2];
    const float* enc_b1   = (const float*)d_in[3];
    const float* enc_w2   = (const float*)d_in[4];
    const float* enc_b2   = (const float*)d_in[5];
    const float* q_weights= (const float*)d_in[6];
    const float* head_w1  = (const float*)d_in[7];
    const float* head_b1  = (const float*)d_in[8];
    const float* head_w2  = (const float*)d_in[9];
    const float* head_b2  = (const float*)d_in[10];
    float* out = (float*)d_out;

    const int n = in_sizes[0] / 32;          // B (even)
    const int half_n = n >> 1;
    const int block = 256;
    const int grid = (half_n + block - 1) / block;
    qrr_kernel<<<grid, block, 0, stream>>>(features, baseline,
                                           enc_w1, enc_b1, enc_w2, enc_b2,
                                           q_weights,
                                           head_w1, head_b1, head_w2, head_b2,
                                           out, half_n);
}